// Round 4
// baseline (493.137 us; speedup 1.0000x reference)
//
#include <hip/hip_runtime.h>
#include <math.h>

// Problem: B=4, S=2048, D=1024, H=16, DK=64.
// out = softmax((q Wq^T)(k Wk^T)^T / 8) (v Wv^T) Wo^T, heads split on D.
//
// Pipeline:
//   1. cast_all: fp32->bf16 for {q,k,v,Wq,Wk,Wv,Wo} in ONE launch
//   2. gemm_qkv: Qp=(q@Wq^T)*(0.125*log2e), Kp=k@Wk^T (bf16 [8192,1024]),
//                VpT = (v@Wv^T) stored transposed [B*1024, 2048] bf16
//   3. attn: flash attention, S^T/O^T formulation, Q-tile 64 (R3: was 128 ->
//            grid 2048, 6 blocks/CU; occupancy was the binding limit at 37%),
//            K-tile 64, no-max exp2 softmax, per-lane denominator,
//            XCD-aware block swizzle (8 K/V panels = 4MB = one L2 per XCD),
//            s_setprio(1) around MFMA clusters (T5).
//   4. gemm_out: out = Xp @ Wo^T (fp32), BK=64 + C^T epilogue -> float4.

#define DEV __device__ __forceinline__

typedef __bf16 bf16x8 __attribute__((ext_vector_type(8)));
typedef __bf16 bf16x2 __attribute__((ext_vector_type(2)));
typedef float f32x4 __attribute__((ext_vector_type(4)));
typedef unsigned int u32x2 __attribute__((ext_vector_type(2)));

typedef __attribute__((address_space(1))) const unsigned int g_u32;
typedef __attribute__((address_space(3))) unsigned int l_u32;

DEV unsigned short f2bf(float x) {  // RNE truncate to bf16
  unsigned int u = __float_as_uint(x);
  u += 0x7fffu + ((u >> 16) & 1u);
  return (unsigned short)(u >> 16);
}

DEV unsigned int pack2bf(float a, float b) {
#if __has_builtin(__builtin_amdgcn_cvt_pk_bf16_f32)
  bf16x2 r = __builtin_amdgcn_cvt_pk_bf16_f32(a, b);
  union { bf16x2 v; unsigned int u; } c;
  c.v = r;
  return c.u;
#else
  unsigned int ua = __float_as_uint(a) + 0x8000u;
  unsigned int ub = __float_as_uint(b) + 0x8000u;
  return (ua >> 16) | (ub & 0xffff0000u);
#endif
}

DEV float fexp2(float x) {
#if __has_builtin(__builtin_amdgcn_exp2f)
  return __builtin_amdgcn_exp2f(x);
#else
  return __expf(x * 0.69314718056f);
#endif
}

DEV void ld16(const unsigned short* g, unsigned short* l) {
  // async global->LDS, 16B per lane; LDS dest = wave-uniform base + lane*16
  __builtin_amdgcn_global_load_lds((g_u32*)g, (l_u32*)l, 16, 0, 0);
}

// One launch for all 7 casts. Blocks 0..24575: q,k,v (8192 blocks each,
// 2M float4 per tensor). Blocks 24576..28671: weights (1024 blocks each).
__global__ __launch_bounds__(256) void cast_all(
    const float* __restrict__ q, const float* __restrict__ k,
    const float* __restrict__ v, const float* __restrict__ w0,
    const float* __restrict__ w1, const float* __restrict__ w2,
    const float* __restrict__ w3, unsigned short* __restrict__ qb,
    unsigned short* __restrict__ kb, unsigned short* __restrict__ vb,
    unsigned short* __restrict__ o0, unsigned short* __restrict__ o1,
    unsigned short* __restrict__ o2, unsigned short* __restrict__ o3) {
  const int bb = blockIdx.x;
  const float* src;
  unsigned short* dst;
  int i;
  if (bb < 24576) {
    const int z = bb >> 13, lb = bb & 8191;
    src = (z == 0) ? q : (z == 1) ? k : v;
    dst = (z == 0) ? qb : (z == 1) ? kb : vb;
    i = lb * 256 + threadIdx.x;
  } else {
    const int t = bb - 24576;
    const int z = t >> 10, lb = t & 1023;
    src = (z == 0) ? w0 : (z == 1) ? w1 : (z == 2) ? w2 : w3;
    dst = (z == 0) ? o0 : (z == 1) ? o1 : (z == 2) ? o2 : o3;
    i = lb * 256 + threadIdx.x;
  }
  float4 vv = reinterpret_cast<const float4*>(src)[i];
  ushort4 o;
  o.x = f2bf(vv.x); o.y = f2bf(vv.y); o.z = f2bf(vv.z); o.w = f2bf(vv.w);
  reinterpret_cast<ushort4*>(dst)[i] = o;
}

// ---- NT GEMM core, BK=64: C[128x128] tile, A [M,1024] bf16 rm, W [N,1024].
// 4 waves, each 64x64 (4x4 MFMA tiles of 16x16x32 bf16). 32 MFMA per barrier
// pair. LDS tiles 128x64 (row stride 128B) with XOR granule swizzle
// (phys_granule = logical ^ (row&7)) -> conflict-free b128 reads.
// SW=true computes C^T (mfma(bF,aF)) -> acc[j][i], lane holds 4 consecutive
// output cols of one row; SW=false computes C -> acc[i][j] (m97 layout).
template <bool SW>
DEV void gemm_core(const unsigned short* __restrict__ A,
                   const unsigned short* __restrict__ W,
                   unsigned short* As, unsigned short* Bs,
                   f32x4 (&acc)[4][4], int tileM, int tileN) {
  const int tid = threadIdx.x;
  const int w = tid >> 6, lane = tid & 63;
  const int wr = (w & 1) * 64, wc = (w >> 1) * 64;
  const int l15 = lane & 15, g4 = lane >> 4, l7 = l15 & 7;
  const int rsub = lane >> 3;            // row within 8-row staging chunk
  const int gsrc = (lane & 7) ^ rsub;    // swizzled source granule (8 shorts)

  const f32x4 fzero = {0.f, 0.f, 0.f, 0.f};
#pragma unroll
  for (int i = 0; i < 4; i++)
#pragma unroll
    for (int j = 0; j < 4; j++) acc[i][j] = fzero;

  for (int k0 = 0; k0 < 1024; k0 += 64) {
#pragma unroll
    for (int j = 0; j < 4; ++j) {
      const int c = w * 4 + j;  // chunk: 8 rows x 128B = 1KB
      ld16(A + (size_t)(tileM + c * 8 + rsub) * 1024 + k0 + gsrc * 8, As + c * 512);
      ld16(W + (size_t)(tileN + c * 8 + rsub) * 1024 + k0 + gsrc * 8, Bs + c * 512);
    }
    __syncthreads();
#pragma unroll
    for (int kc = 0; kc < 2; kc++) {
      const int ph = ((kc * 4 + g4) ^ l7) * 8;
      bf16x8 aF[4], bF[4];
#pragma unroll
      for (int i = 0; i < 4; i++)
        aF[i] = *reinterpret_cast<const bf16x8*>(&As[(wr + i * 16 + l15) * 64 + ph]);
#pragma unroll
      for (int j = 0; j < 4; j++)
        bF[j] = *reinterpret_cast<const bf16x8*>(&Bs[(wc + j * 16 + l15) * 64 + ph]);
#pragma unroll
      for (int i = 0; i < 4; i++)
#pragma unroll
        for (int j = 0; j < 4; j++) {
          if (SW)
            acc[j][i] = __builtin_amdgcn_mfma_f32_16x16x32_bf16(bF[j], aF[i], acc[j][i], 0, 0, 0);
          else
            acc[i][j] = __builtin_amdgcn_mfma_f32_16x16x32_bf16(aF[i], bF[j], acc[i][j], 0, 0, 0);
        }
    }
    __syncthreads();
  }
}

__global__ __launch_bounds__(256) void gemm_qkv(
    const unsigned short* __restrict__ qb, const unsigned short* __restrict__ kb,
    const unsigned short* __restrict__ vb, const unsigned short* __restrict__ Wq,
    const unsigned short* __restrict__ Wk, const unsigned short* __restrict__ Wv,
    unsigned short* __restrict__ Qp, unsigned short* __restrict__ Kp,
    unsigned short* __restrict__ VpT) {
  __shared__ __align__(16) unsigned short As[128 * 64];
  __shared__ __align__(16) unsigned short Bs[128 * 64];
  const int z = blockIdx.z;
  const int tileM = blockIdx.x * 128, tileN = blockIdx.y * 128;
  const int tid = threadIdx.x, w = tid >> 6, lane = tid & 63;
  const int wr = (w & 1) * 64, wc = (w >> 1) * 64;
  const int l15 = lane & 15, g4 = lane >> 4;
  f32x4 acc[4][4];

  if (z < 2) {
    // C^T core: lane holds row tileM+wr+i*16+l15, cols +wc+j*16+g4*4+(0..3)
    gemm_core<true>((z == 0) ? qb : kb, (z == 0) ? Wq : Wk, As, Bs, acc, tileM, tileN);
    // fold score scale 1/8 AND log2(e) into Q (exp2-domain softmax downstream)
    const float qs = (z == 0) ? 0.125f * 1.44269504089f : 1.0f;
    unsigned short* C = (z == 0) ? Qp : Kp;
#pragma unroll
    for (int i = 0; i < 4; i++) {
      const size_t row = (size_t)(tileM + wr + i * 16 + l15);
#pragma unroll
      for (int j = 0; j < 4; j++) {
        const int col = tileN + wc + j * 16 + g4 * 4;
        ushort4 pk;
        pk.x = f2bf(acc[j][i][0] * qs); pk.y = f2bf(acc[j][i][1] * qs);
        pk.z = f2bf(acc[j][i][2] * qs); pk.w = f2bf(acc[j][i][3] * qs);
        *reinterpret_cast<ushort4*>(&C[row * 1024 + col]) = pk;
      }
    }
  } else {
    gemm_core<false>(vb, Wv, As, Bs, acc, tileM, tileN);
    // transposed store: VpT[(b*1024 + col)*2048 + s], 4 contiguous s per lane
    const int b = tileM / 2048, s0 = tileM % 2048;
#pragma unroll
    for (int i = 0; i < 4; i++)
#pragma unroll
      for (int j = 0; j < 4; j++) {
        int col = tileN + wc + j * 16 + l15;
        int s = s0 + wr + i * 16 + g4 * 4;
        ushort4 pk;
        pk.x = f2bf(acc[i][j][0]); pk.y = f2bf(acc[i][j][1]);
        pk.z = f2bf(acc[i][j][2]); pk.w = f2bf(acc[i][j][3]);
        *reinterpret_cast<ushort4*>(&VpT[(size_t)(b * 1024 + col) * 2048 + s]) = pk;
      }
  }
}

__global__ __launch_bounds__(256) void gemm_out(
    const unsigned short* __restrict__ Xp, const unsigned short* __restrict__ Wo,
    float* __restrict__ out) {
  __shared__ __align__(16) unsigned short As[128 * 64];
  __shared__ __align__(16) unsigned short Bs[128 * 64];
  const int tileM = blockIdx.x * 128, tileN = blockIdx.y * 128;
  f32x4 acc[4][4];
  gemm_core<true>(Xp, Wo, As, Bs, acc, tileM, tileN);
  const int tid = threadIdx.x, w = tid >> 6, lane = tid & 63;
  const int wr = (w & 1) * 64, wc = (w >> 1) * 64;
  const int l15 = lane & 15, g4 = lane >> 4;
#pragma unroll
  for (int i = 0; i < 4; i++) {
    const size_t row = (size_t)(tileM + wr + i * 16 + l15);
#pragma unroll
    for (int j = 0; j < 4; j++) {
      const int col = tileN + wc + j * 16 + g4 * 4;
      *reinterpret_cast<f32x4*>(&out[row * 1024 + col]) = acc[j][i];
    }
  }
}

// ---- Flash attention, S^T/O^T formulation, no-max softmax, QBLK=64.
// R3: grid 2048 blocks (32 q-tiles x 64 bh). Occupancy was grid-limited at
// 37% (1024 blocks = 4/CU); now LDS-limited at 6 blocks/CU (~75%).
// XCD swizzle: nid=(bid&7)*256+bid>>3 -> each XCD sees 8 (b,h) panels = 4MB.
__global__ __launch_bounds__(256, 6) void attn(
    const unsigned short* __restrict__ Qp, const unsigned short* __restrict__ Kp,
    const unsigned short* __restrict__ VpT, unsigned short* __restrict__ Xp) {
  __shared__ __align__(16) unsigned short Ks[64 * 64];      // [kp][d], 16B-gran swz
  __shared__ __align__(16) unsigned short Vs[64 * 64];      // [d][kp], 16B-gran swz
  __shared__ __align__(16) unsigned short Ps[4 * 16 * 64];  // per-wave P[m][kp], 8B swz

  const int bid = blockIdx.x;
  const int nid = (bid & 7) * 256 + (bid >> 3);  // bijective, 2048%8==0
  const int qt = nid & 31, bh = nid >> 5;
  const int b = bh >> 4, h = bh & 15;
  const int q0 = qt * 64;
  const int tid = threadIdx.x, w = tid >> 6, lane = tid & 63;
  const int l15 = lane & 15, g4 = lane >> 4;
  const int l7 = l15 & 7;

  const int rsub = lane >> 3;
  const int gsrc = (lane & 7) ^ rsub;

  // Q rows: wave w owns rows q0 + w*16 + l15 (16 rows/wave)
  bf16x8 qf[2];
  {
    const unsigned short* Qrow =
        Qp + (size_t)(b * 2048 + q0 + w * 16 + l15) * 1024 + h * 64;
    qf[0] = *reinterpret_cast<const bf16x8*>(Qrow + g4 * 8);
    qf[1] = *reinterpret_cast<const bf16x8*>(Qrow + 32 + g4 * 8);
  }

  const f32x4 fzero = {0.f, 0.f, 0.f, 0.f};
  f32x4 o[4];
#pragma unroll
  for (int dj = 0; dj < 4; dj++) o[dj] = fzero;
  float l_i = 0.f;  // per-lane partial denominator

  const unsigned short* Kbase = Kp + (size_t)(b * 2048) * 1024 + h * 64;
  const unsigned short* Vbase = VpT + (size_t)(b * 1024 + h * 64) * 2048;
  unsigned short* Pw = Ps + w * 1024;

  for (int kt = 0; kt < 2048; kt += 64) {
#pragma unroll
    for (int j = 0; j < 2; ++j) {
      const int c = w * 2 + j;  // 8 rows x 128B per chunk, granule-permuted source
      ld16(Kbase + (size_t)(kt + c * 8 + rsub) * 1024 + gsrc * 8, Ks + c * 512);
      ld16(Vbase + (size_t)(c * 8 + rsub) * 2048 + kt + gsrc * 8, Vs + c * 512);
    }
    __syncthreads();  // drains this tile's loads

    // S^T = K Q^T : sv[jt][r] = S'[m=l15][kp = kt + jt*16 + g4*4 + r]
    f32x4 sv[4];
    __builtin_amdgcn_s_setprio(1);
#pragma unroll
    for (int jt = 0; jt < 4; jt++) {
      const int row = jt * 16 + l15;
      const int s0 = g4 ^ l7;
      bf16x8 kf0 = *reinterpret_cast<const bf16x8*>(&Ks[row * 64 + s0 * 8]);
      bf16x8 kf1 = *reinterpret_cast<const bf16x8*>(&Ks[row * 64 + (s0 ^ 4) * 8]);
      f32x4 z = fzero;
      z = __builtin_amdgcn_mfma_f32_16x16x32_bf16(kf0, qf[0], z, 0, 0, 0);
      z = __builtin_amdgcn_mfma_f32_16x16x32_bf16(kf1, qf[1], z, 0, 0, 0);
      sv[jt] = z;
    }
    __builtin_amdgcn_s_setprio(0);

    // P = exp2(S') ; accumulate per-lane denominator (no shuffles, no max)
    {
      float rs = 0.f;
#pragma unroll
      for (int jt = 0; jt < 4; jt++)
#pragma unroll
        for (int r = 0; r < 4; r++) {
          sv[jt][r] = fexp2(sv[jt][r]);
          rs += sv[jt][r];
        }
      l_i += rs;
    }

    // V fragments
    bf16x8 vf[2][4];
#pragma unroll
    for (int kc = 0; kc < 2; kc++)
#pragma unroll
      for (int dj = 0; dj < 4; dj++)
        vf[kc][dj] = *reinterpret_cast<const bf16x8*>(
            &Vs[(dj * 16 + l15) * 64 + ((kc * 4 + g4) ^ l7) * 8]);

    // P write: row l15, 4 consecutive kp per lane -> b64, 8B-granule swizzle
#pragma unroll
    for (int jt = 0; jt < 4; jt++) {
      u32x2 pk;
      pk.x = pack2bf(sv[jt][0], sv[jt][1]);
      pk.y = pack2bf(sv[jt][2], sv[jt][3]);
      const int slot = (jt * 4 + g4) ^ l15;
      *reinterpret_cast<u32x2*>(&Pw[l15 * 64 + slot * 4]) = pk;
    }
    // O^T += V^T P^T (in-wave DS ordering: write->read safe)
    __builtin_amdgcn_s_setprio(1);
#pragma unroll
    for (int kc = 0; kc < 2; kc++) {
      const int sA = (kc * 8 + g4 * 2) ^ l15;
      const int sB = (kc * 8 + g4 * 2 + 1) ^ l15;
      u32x2 pa = *reinterpret_cast<const u32x2*>(&Pw[l15 * 64 + sA * 4]);
      u32x2 pb = *reinterpret_cast<const u32x2*>(&Pw[l15 * 64 + sB * 4]);
      union { unsigned int u[4]; bf16x8 v; } pf;
      pf.u[0] = pa.x; pf.u[1] = pa.y; pf.u[2] = pb.x; pf.u[3] = pb.y;
#pragma unroll
      for (int dj = 0; dj < 4; dj++)
        o[dj] = __builtin_amdgcn_mfma_f32_16x16x32_bf16(vf[kc][dj], pf.v,
                                                        o[dj], 0, 0, 0);
    }
    __builtin_amdgcn_s_setprio(0);
    __syncthreads();  // all waves done reading Ks/Vs before next staging
  }

  // epilogue: reduce denominator over the 4 g4 groups, then store O^T
  {
    float rs = l_i;
    rs += __shfl_xor(rs, 16);
    rs += __shfl_xor(rs, 32);
    const float inv = 1.f / rs;
    const size_t row = (size_t)(b * 2048 + q0 + w * 16 + l15);
#pragma unroll
    for (int dj = 0; dj < 4; dj++) {
      ushort4 pk;
      pk.x = f2bf(o[dj][0] * inv);
      pk.y = f2bf(o[dj][1] * inv);
      pk.z = f2bf(o[dj][2] * inv);
      pk.w = f2bf(o[dj][3] * inv);
      *reinterpret_cast<ushort4*>(&Xp[row * 1024 + h * 64 + dj * 16 + g4 * 4]) = pk;
    }
  }
}

extern "C" void kernel_launch(void* const* d_in, const int* in_sizes, int n_in,
                              void* d_out, int out_size, void* d_ws, size_t ws_size,
                              hipStream_t stream) {
  const float* q  = (const float*)d_in[0];
  const float* k  = (const float*)d_in[1];
  const float* v  = (const float*)d_in[2];
  // d_in[3] mask: unused by the reference
  const float* Wq = (const float*)d_in[4];
  const float* Wk = (const float*)d_in[5];
  const float* Wv = (const float*)d_in[6];
  const float* Wo = (const float*)d_in[7];
  float* out = (float*)d_out;

  char* ws = (char*)d_ws;
  const size_t MB = 1u << 20;
  unsigned short* qb  = (unsigned short*)(ws + 0 * MB);    // 16 MB each
  unsigned short* kb  = (unsigned short*)(ws + 16 * MB);
  unsigned short* vb  = (unsigned short*)(ws + 32 * MB);
  unsigned short* wqb = (unsigned short*)(ws + 48 * MB);   // 2 MB each
  unsigned short* wkb = (unsigned short*)(ws + 50 * MB);
  unsigned short* wvb = (unsigned short*)(ws + 52 * MB);
  unsigned short* wob = (unsigned short*)(ws + 54 * MB);
  unsigned short* Qp  = (unsigned short*)(ws + 56 * MB);   // 16 MB (pre-scaled)
  unsigned short* Kp  = (unsigned short*)(ws + 72 * MB);   // 16 MB
  unsigned short* VpT = (unsigned short*)(ws + 88 * MB);   // 16 MB, [B*1024, 2048]
  unsigned short* Xp  = (unsigned short*)(ws + 104 * MB);  // 16 MB

  // 3*8192 blocks (q,k,v) + 4*1024 blocks (weights) = 28672
  cast_all<<<dim3(28672), 256, 0, stream>>>(q, k, v, Wq, Wk, Wv, Wo,
                                            qb, kb, vb, wqb, wkb, wvb, wob);

  dim3 gq(64, 8, 3);
  gemm_qkv<<<gq, 256, 0, stream>>>(qb, kb, vb, wqb, wkb, wvb, Qp, Kp, VpT);

  attn<<<dim3(2048), 256, 0, stream>>>(Qp, Kp, VpT, Xp);

  dim3 go(64, 8, 1);
  gemm_out<<<go, 256, 0, stream>>>(Xp, wob, out);
}

// Round 7
// 365.630 us; speedup vs baseline: 1.3487x; 1.3487x over previous
//
#include <hip/hip_runtime.h>
#include <math.h>

// Problem: B=4, S=2048, D=1024, H=16, DK=64.
// out = softmax((q Wq^T)(k Wk^T)^T / 8) (v Wv^T) Wo^T, heads split on D.
//
// Pipeline:
//   1. cast_all: fp32->bf16 for {q,k,v,Wq,Wk,Wv,Wo} in ONE launch
//   2. gemm_qkv: Qp=(q@Wq^T)*(0.125*log2e), Kp=k@Wk^T (bf16 [8192,1024]),
//                VpT = (v@Wv^T) stored transposed [B*1024, 2048] bf16
//   3. attn: flash attention, S^T/O^T formulation, Q-tile 128 (R5: reverted
//            from R4's QBLK=64 which tripled HBM traffic and halved
//            arithmetic intensity), K-tile 64, DOUBLE-BUFFERED K/V staging
//            (T3-minimum: stage t+1 before compute t, ONE barrier per tile),
//            no-max exp2 softmax, per-lane denominator,
//            XCD-aware block swizzle, s_setprio(1) around MFMA (T5).
//   4. gemm_out: out = Xp @ Wo^T (fp32), BK=64 + C^T epilogue -> float4.

#define DEV __device__ __forceinline__

typedef __bf16 bf16x8 __attribute__((ext_vector_type(8)));
typedef __bf16 bf16x2 __attribute__((ext_vector_type(2)));
typedef float f32x4 __attribute__((ext_vector_type(4)));
typedef unsigned int u32x2 __attribute__((ext_vector_type(2)));

typedef __attribute__((address_space(1))) const unsigned int g_u32;
typedef __attribute__((address_space(3))) unsigned int l_u32;

DEV unsigned short f2bf(float x) {  // RNE truncate to bf16
  unsigned int u = __float_as_uint(x);
  u += 0x7fffu + ((u >> 16) & 1u);
  return (unsigned short)(u >> 16);
}

DEV unsigned int pack2bf(float a, float b) {
#if __has_builtin(__builtin_amdgcn_cvt_pk_bf16_f32)
  bf16x2 r = __builtin_amdgcn_cvt_pk_bf16_f32(a, b);
  union { bf16x2 v; unsigned int u; } c;
  c.v = r;
  return c.u;
#else
  unsigned int ua = __float_as_uint(a) + 0x8000u;
  unsigned int ub = __float_as_uint(b) + 0x8000u;
  return (ua >> 16) | (ub & 0xffff0000u);
#endif
}

DEV float fexp2(float x) {
#if __has_builtin(__builtin_amdgcn_exp2f)
  return __builtin_amdgcn_exp2f(x);
#else
  return __expf(x * 0.69314718056f);
#endif
}

DEV void ld16(const unsigned short* g, unsigned short* l) {
  // async global->LDS, 16B per lane; LDS dest = wave-uniform base + lane*16
  __builtin_amdgcn_global_load_lds((g_u32*)g, (l_u32*)l, 16, 0, 0);
}

// One launch for all 7 casts. Blocks 0..24575: q,k,v (8192 blocks each,
// 2M float4 per tensor). Blocks 24576..28671: weights (1024 blocks each).
__global__ __launch_bounds__(256) void cast_all(
    const float* __restrict__ q, const float* __restrict__ k,
    const float* __restrict__ v, const float* __restrict__ w0,
    const float* __restrict__ w1, const float* __restrict__ w2,
    const float* __restrict__ w3, unsigned short* __restrict__ qb,
    unsigned short* __restrict__ kb, unsigned short* __restrict__ vb,
    unsigned short* __restrict__ o0, unsigned short* __restrict__ o1,
    unsigned short* __restrict__ o2, unsigned short* __restrict__ o3) {
  const int bb = blockIdx.x;
  const float* src;
  unsigned short* dst;
  int i;
  if (bb < 24576) {
    const int z = bb >> 13, lb = bb & 8191;
    src = (z == 0) ? q : (z == 1) ? k : v;
    dst = (z == 0) ? qb : (z == 1) ? kb : vb;
    i = lb * 256 + threadIdx.x;
  } else {
    const int t = bb - 24576;
    const int z = t >> 10, lb = t & 1023;
    src = (z == 0) ? w0 : (z == 1) ? w1 : (z == 2) ? w2 : w3;
    dst = (z == 0) ? o0 : (z == 1) ? o1 : (z == 2) ? o2 : o3;
    i = lb * 256 + threadIdx.x;
  }
  float4 vv = reinterpret_cast<const float4*>(src)[i];
  ushort4 o;
  o.x = f2bf(vv.x); o.y = f2bf(vv.y); o.z = f2bf(vv.z); o.w = f2bf(vv.w);
  reinterpret_cast<ushort4*>(dst)[i] = o;
}

// ---- NT GEMM core, BK=64: C[128x128] tile, A [M,1024] bf16 rm, W [N,1024].
// 4 waves, each 64x64 (4x4 MFMA tiles of 16x16x32 bf16). 32 MFMA per barrier
// pair. LDS tiles 128x64 (row stride 128B) with XOR granule swizzle
// (phys_granule = logical ^ (row&7)) -> conflict-free b128 reads.
// SW=true computes C^T (mfma(bF,aF)) -> acc[j][i], lane holds 4 consecutive
// output cols of one row; SW=false computes C -> acc[i][j] (m97 layout).
template <bool SW>
DEV void gemm_core(const unsigned short* __restrict__ A,
                   const unsigned short* __restrict__ W,
                   unsigned short* As, unsigned short* Bs,
                   f32x4 (&acc)[4][4], int tileM, int tileN) {
  const int tid = threadIdx.x;
  const int w = tid >> 6, lane = tid & 63;
  const int wr = (w & 1) * 64, wc = (w >> 1) * 64;
  const int l15 = lane & 15, g4 = lane >> 4, l7 = l15 & 7;
  const int rsub = lane >> 3;            // row within 8-row staging chunk
  const int gsrc = (lane & 7) ^ rsub;    // swizzled source granule (8 shorts)

  const f32x4 fzero = {0.f, 0.f, 0.f, 0.f};
#pragma unroll
  for (int i = 0; i < 4; i++)
#pragma unroll
    for (int j = 0; j < 4; j++) acc[i][j] = fzero;

  for (int k0 = 0; k0 < 1024; k0 += 64) {
#pragma unroll
    for (int j = 0; j < 4; ++j) {
      const int c = w * 4 + j;  // chunk: 8 rows x 128B = 1KB
      ld16(A + (size_t)(tileM + c * 8 + rsub) * 1024 + k0 + gsrc * 8, As + c * 512);
      ld16(W + (size_t)(tileN + c * 8 + rsub) * 1024 + k0 + gsrc * 8, Bs + c * 512);
    }
    __syncthreads();
#pragma unroll
    for (int kc = 0; kc < 2; kc++) {
      const int ph = ((kc * 4 + g4) ^ l7) * 8;
      bf16x8 aF[4], bF[4];
#pragma unroll
      for (int i = 0; i < 4; i++)
        aF[i] = *reinterpret_cast<const bf16x8*>(&As[(wr + i * 16 + l15) * 64 + ph]);
#pragma unroll
      for (int j = 0; j < 4; j++)
        bF[j] = *reinterpret_cast<const bf16x8*>(&Bs[(wc + j * 16 + l15) * 64 + ph]);
#pragma unroll
      for (int i = 0; i < 4; i++)
#pragma unroll
        for (int j = 0; j < 4; j++) {
          if (SW)
            acc[j][i] = __builtin_amdgcn_mfma_f32_16x16x32_bf16(bF[j], aF[i], acc[j][i], 0, 0, 0);
          else
            acc[i][j] = __builtin_amdgcn_mfma_f32_16x16x32_bf16(aF[i], bF[j], acc[i][j], 0, 0, 0);
        }
    }
    __syncthreads();
  }
}

__global__ __launch_bounds__(256) void gemm_qkv(
    const unsigned short* __restrict__ qb, const unsigned short* __restrict__ kb,
    const unsigned short* __restrict__ vb, const unsigned short* __restrict__ Wq,
    const unsigned short* __restrict__ Wk, const unsigned short* __restrict__ Wv,
    unsigned short* __restrict__ Qp, unsigned short* __restrict__ Kp,
    unsigned short* __restrict__ VpT) {
  __shared__ __align__(16) unsigned short As[128 * 64];
  __shared__ __align__(16) unsigned short Bs[128 * 64];
  const int z = blockIdx.z;
  const int tileM = blockIdx.x * 128, tileN = blockIdx.y * 128;
  const int tid = threadIdx.x, w = tid >> 6, lane = tid & 63;
  const int wr = (w & 1) * 64, wc = (w >> 1) * 64;
  const int l15 = lane & 15, g4 = lane >> 4;
  f32x4 acc[4][4];

  if (z < 2) {
    // C^T core: lane holds row tileM+wr+i*16+l15, cols +wc+j*16+g4*4+(0..3)
    gemm_core<true>((z == 0) ? qb : kb, (z == 0) ? Wq : Wk, As, Bs, acc, tileM, tileN);
    // fold score scale 1/8 AND log2(e) into Q (exp2-domain softmax downstream)
    const float qs = (z == 0) ? 0.125f * 1.44269504089f : 1.0f;
    unsigned short* C = (z == 0) ? Qp : Kp;
#pragma unroll
    for (int i = 0; i < 4; i++) {
      const size_t row = (size_t)(tileM + wr + i * 16 + l15);
#pragma unroll
      for (int j = 0; j < 4; j++) {
        const int col = tileN + wc + j * 16 + g4 * 4;
        ushort4 pk;
        pk.x = f2bf(acc[j][i][0] * qs); pk.y = f2bf(acc[j][i][1] * qs);
        pk.z = f2bf(acc[j][i][2] * qs); pk.w = f2bf(acc[j][i][3] * qs);
        *reinterpret_cast<ushort4*>(&C[row * 1024 + col]) = pk;
      }
    }
  } else {
    gemm_core<false>(vb, Wv, As, Bs, acc, tileM, tileN);
    // transposed store: VpT[(b*1024 + col)*2048 + s], 4 contiguous s per lane
    const int b = tileM / 2048, s0 = tileM % 2048;
#pragma unroll
    for (int i = 0; i < 4; i++)
#pragma unroll
      for (int j = 0; j < 4; j++) {
        int col = tileN + wc + j * 16 + l15;
        int s = s0 + wr + i * 16 + g4 * 4;
        ushort4 pk;
        pk.x = f2bf(acc[i][j][0]); pk.y = f2bf(acc[i][j][1]);
        pk.z = f2bf(acc[i][j][2]); pk.w = f2bf(acc[i][j][3]);
        *reinterpret_cast<ushort4*>(&VpT[(size_t)(b * 1024 + col) * 2048 + s]) = pk;
      }
  }
}

__global__ __launch_bounds__(256) void gemm_out(
    const unsigned short* __restrict__ Xp, const unsigned short* __restrict__ Wo,
    float* __restrict__ out) {
  __shared__ __align__(16) unsigned short As[128 * 64];
  __shared__ __align__(16) unsigned short Bs[128 * 64];
  const int tileM = blockIdx.x * 128, tileN = blockIdx.y * 128;
  f32x4 acc[4][4];
  gemm_core<true>(Xp, Wo, As, Bs, acc, tileM, tileN);
  const int tid = threadIdx.x, w = tid >> 6, lane = tid & 63;
  const int wr = (w & 1) * 64, wc = (w >> 1) * 64;
  const int l15 = lane & 15, g4 = lane >> 4;
#pragma unroll
  for (int i = 0; i < 4; i++) {
    const size_t row = (size_t)(tileM + wr + i * 16 + l15);
#pragma unroll
    for (int j = 0; j < 4; j++) {
      const int col = tileN + wc + j * 16 + g4 * 4;
      *reinterpret_cast<f32x4*>(&out[row * 1024 + col]) = acc[j][i];
    }
  }
}

// ---- Flash attention, S^T/O^T, no-max softmax, QBLK=128 (R3 shape).
// R5: double-buffered K/V staging. Per tile: stage(t+1) -> compute(t) ->
// ONE barrier (drains t+1's loads, which had the whole compute phase in
// flight). LDS 40KB -> exactly 4 blocks/CU (same occupancy as R3's 24KB,
// which was grid-capped at 4). Grid 1024, XCD-swizzled (8 panels/XCD = L2).
__global__ __launch_bounds__(256, 4) void attn(
    const unsigned short* __restrict__ Qp, const unsigned short* __restrict__ Kp,
    const unsigned short* __restrict__ VpT, unsigned short* __restrict__ Xp) {
  __shared__ __align__(16) unsigned short Ks[2 * 64 * 64];  // [buf][kp][d], 16B-gran swz
  __shared__ __align__(16) unsigned short Vs[2 * 64 * 64];  // [buf][d][kp], 16B-gran swz
  __shared__ __align__(16) unsigned short Ps[4 * 16 * 64];  // per-wave P[m][kp], 8B swz

  const int bid = blockIdx.x;
  const int nid = (bid & 7) * 128 + (bid >> 3);  // bijective, 1024%8==0
  const int qt = nid & 15, bh = nid >> 4;
  const int b = bh >> 4, h = bh & 15;
  const int q0 = qt * 128;
  const int tid = threadIdx.x, w = tid >> 6, lane = tid & 63;
  const int l15 = lane & 15, g4 = lane >> 4;
  const int l7 = l15 & 7;

  const int rsub = lane >> 3;
  const int gsrc = (lane & 7) ^ rsub;

  bf16x8 qf[2][2];
#pragma unroll
  for (int mi = 0; mi < 2; mi++) {
    const unsigned short* Qrow =
        Qp + (size_t)(b * 2048 + q0 + w * 32 + mi * 16 + l15) * 1024 + h * 64;
    qf[mi][0] = *reinterpret_cast<const bf16x8*>(Qrow + g4 * 8);
    qf[mi][1] = *reinterpret_cast<const bf16x8*>(Qrow + 32 + g4 * 8);
  }

  const f32x4 fzero = {0.f, 0.f, 0.f, 0.f};
  f32x4 o[2][4];
#pragma unroll
  for (int mi = 0; mi < 2; mi++)
#pragma unroll
    for (int dj = 0; dj < 4; dj++) o[mi][dj] = fzero;
  float l_i[2] = {0.f, 0.f};  // per-lane partial denominators

  const unsigned short* Kbase = Kp + (size_t)(b * 2048) * 1024 + h * 64;
  const unsigned short* Vbase = VpT + (size_t)(b * 1024 + h * 64) * 2048;
  unsigned short* Pw = Ps + w * 1024;

  const int c = w * 2;  // this wave's two staging chunks are c, c+1

  // prologue: stage tile 0 into buffer 0
#pragma unroll
  for (int j = 0; j < 2; ++j) {
    ld16(Kbase + (size_t)((c + j) * 8 + rsub) * 1024 + gsrc * 8, Ks + (c + j) * 512);
    ld16(Vbase + (size_t)((c + j) * 8 + rsub) * 2048 + gsrc * 8, Vs + (c + j) * 512);
  }
  __syncthreads();  // implicit vmcnt(0): tile 0 resident

  int cur = 0;
  for (int t = 0; t < 32; ++t) {
    const int kt = t * 64;
    unsigned short* Kc = Ks + cur * 4096;
    unsigned short* Vc = Vs + cur * 4096;

    // stage tile t+1 into the other buffer (loads fly during compute)
    if (t < 31) {
      unsigned short* Kn = Ks + (cur ^ 1) * 4096;
      unsigned short* Vn = Vs + (cur ^ 1) * 4096;
      const int ktn = kt + 64;
#pragma unroll
      for (int j = 0; j < 2; ++j) {
        ld16(Kbase + (size_t)(ktn + (c + j) * 8 + rsub) * 1024 + gsrc * 8,
             Kn + (c + j) * 512);
        ld16(Vbase + (size_t)((c + j) * 8 + rsub) * 2048 + ktn + gsrc * 8,
             Vn + (c + j) * 512);
      }
    }

    // S^T = K Q^T : sv[mi][jt][r] = S'[m][kp = kt + jt*16 + g4*4 + r]
    f32x4 sv[2][4];
    __builtin_amdgcn_s_setprio(1);
#pragma unroll
    for (int jt = 0; jt < 4; jt++) {
      const int row = jt * 16 + l15;
      const int s0 = g4 ^ l7;
      bf16x8 kf0 = *reinterpret_cast<const bf16x8*>(&Kc[row * 64 + s0 * 8]);
      bf16x8 kf1 = *reinterpret_cast<const bf16x8*>(&Kc[row * 64 + (s0 ^ 4) * 8]);
#pragma unroll
      for (int mi = 0; mi < 2; mi++) {
        f32x4 z = fzero;
        z = __builtin_amdgcn_mfma_f32_16x16x32_bf16(kf0, qf[mi][0], z, 0, 0, 0);
        z = __builtin_amdgcn_mfma_f32_16x16x32_bf16(kf1, qf[mi][1], z, 0, 0, 0);
        sv[mi][jt] = z;
      }
    }
    __builtin_amdgcn_s_setprio(0);

    // P = exp2(S') ; accumulate per-lane denominator (no shuffles, no max)
#pragma unroll
    for (int mi = 0; mi < 2; mi++) {
      float rs = 0.f;
#pragma unroll
      for (int jt = 0; jt < 4; jt++)
#pragma unroll
        for (int r = 0; r < 4; r++) {
          sv[mi][jt][r] = fexp2(sv[mi][jt][r]);
          rs += sv[mi][jt][r];
        }
      l_i[mi] += rs;
    }

    // V fragments: read once, reused for both m-tiles
    bf16x8 vf[2][4];
#pragma unroll
    for (int kc = 0; kc < 2; kc++)
#pragma unroll
      for (int dj = 0; dj < 4; dj++)
        vf[kc][dj] = *reinterpret_cast<const bf16x8*>(
            &Vc[(dj * 16 + l15) * 64 + ((kc * 4 + g4) ^ l7) * 8]);

#pragma unroll
    for (int mi = 0; mi < 2; mi++) {
      // P write: row l15, 4 consecutive kp per lane -> b64, 8B-granule swizzle
#pragma unroll
      for (int jt = 0; jt < 4; jt++) {
        u32x2 pk;
        pk.x = pack2bf(sv[mi][jt][0], sv[mi][jt][1]);
        pk.y = pack2bf(sv[mi][jt][2], sv[mi][jt][3]);
        const int slot = (jt * 4 + g4) ^ l15;
        *reinterpret_cast<u32x2*>(&Pw[l15 * 64 + slot * 4]) = pk;
      }
      // O^T += V^T P^T (in-wave DS ordering: write->read safe)
      __builtin_amdgcn_s_setprio(1);
#pragma unroll
      for (int kc = 0; kc < 2; kc++) {
        const int sA = (kc * 8 + g4 * 2) ^ l15;
        const int sB = (kc * 8 + g4 * 2 + 1) ^ l15;
        u32x2 pa = *reinterpret_cast<const u32x2*>(&Pw[l15 * 64 + sA * 4]);
        u32x2 pb = *reinterpret_cast<const u32x2*>(&Pw[l15 * 64 + sB * 4]);
        union { unsigned int u[4]; bf16x8 v; } pf;
        pf.u[0] = pa.x; pf.u[1] = pa.y; pf.u[2] = pb.x; pf.u[3] = pb.y;
#pragma unroll
        for (int dj = 0; dj < 4; dj++)
          o[mi][dj] = __builtin_amdgcn_mfma_f32_16x16x32_bf16(vf[kc][dj], pf.v,
                                                             o[mi][dj], 0, 0, 0);
      }
      __builtin_amdgcn_s_setprio(0);
    }

    // ONE barrier per tile: (a) all waves done reading buf[cur] before it is
    // restaged next iter; (b) implicit vmcnt(0) drains t+1's loads, which
    // have been in flight across the whole compute phase above.
    __syncthreads();
    cur ^= 1;
  }

  // epilogue: reduce denominator over the 4 g4 groups, then store O^T
#pragma unroll
  for (int mi = 0; mi < 2; mi++) {
    float rs = l_i[mi];
    rs += __shfl_xor(rs, 16);
    rs += __shfl_xor(rs, 32);
    const float inv = 1.f / rs;
    const size_t row = (size_t)(b * 2048 + q0 + w * 32 + mi * 16 + l15);
#pragma unroll
    for (int dj = 0; dj < 4; dj++) {
      ushort4 pk;
      pk.x = f2bf(o[mi][dj][0] * inv);
      pk.y = f2bf(o[mi][dj][1] * inv);
      pk.z = f2bf(o[mi][dj][2] * inv);
      pk.w = f2bf(o[mi][dj][3] * inv);
      *reinterpret_cast<ushort4*>(&Xp[row * 1024 + h * 64 + dj * 16 + g4 * 4]) = pk;
    }
  }
}

extern "C" void kernel_launch(void* const* d_in, const int* in_sizes, int n_in,
                              void* d_out, int out_size, void* d_ws, size_t ws_size,
                              hipStream_t stream) {
  const float* q  = (const float*)d_in[0];
  const float* k  = (const float*)d_in[1];
  const float* v  = (const float*)d_in[2];
  // d_in[3] mask: unused by the reference
  const float* Wq = (const float*)d_in[4];
  const float* Wk = (const float*)d_in[5];
  const float* Wv = (const float*)d_in[6];
  const float* Wo = (const float*)d_in[7];
  float* out = (float*)d_out;

  char* ws = (char*)d_ws;
  const size_t MB = 1u << 20;
  unsigned short* qb  = (unsigned short*)(ws + 0 * MB);    // 16 MB each
  unsigned short* kb  = (unsigned short*)(ws + 16 * MB);
  unsigned short* vb  = (unsigned short*)(ws + 32 * MB);
  unsigned short* wqb = (unsigned short*)(ws + 48 * MB);   // 2 MB each
  unsigned short* wkb = (unsigned short*)(ws + 50 * MB);
  unsigned short* wvb = (unsigned short*)(ws + 52 * MB);
  unsigned short* wob = (unsigned short*)(ws + 54 * MB);
  unsigned short* Qp  = (unsigned short*)(ws + 56 * MB);   // 16 MB (pre-scaled)
  unsigned short* Kp  = (unsigned short*)(ws + 72 * MB);   // 16 MB
  unsigned short* VpT = (unsigned short*)(ws + 88 * MB);   // 16 MB, [B*1024, 2048]
  unsigned short* Xp  = (unsigned short*)(ws + 104 * MB);  // 16 MB

  // 3*8192 blocks (q,k,v) + 4*1024 blocks (weights) = 28672
  cast_all<<<dim3(28672), 256, 0, stream>>>(q, k, v, Wq, Wk, Wv, Wo,
                                            qb, kb, vb, wqb, wkb, wvb, wob);

  dim3 gq(64, 8, 3);
  gemm_qkv<<<gq, 256, 0, stream>>>(qb, kb, vb, wqb, wkb, wvb, Qp, Kp, VpT);

  attn<<<dim3(1024), 256, 0, stream>>>(Qp, Kp, VpT, Xp);

  dim3 go(64, 8, 1);
  gemm_out<<<go, 256, 0, stream>>>(Xp, wob, out);
}

// Round 9
// 358.872 us; speedup vs baseline: 1.3741x; 1.0188x over previous
//
#include <hip/hip_runtime.h>
#include <math.h>

// Problem: B=4, S=2048, D=1024, H=16, DK=64.
// out = softmax((q Wq^T)(k Wk^T)^T / 8) (v Wv^T) Wo^T, heads split on D.
//
// Pipeline:
//   1. cast_all: fp32->bf16 for {q,k,v,Wq,Wk,Wv,Wo} in ONE launch
//   2. gemm_qkv: Qp=(q@Wq^T)*(0.125*log2e), Kp=k@Wk^T (bf16 [8192,1024]),
//                VpT = (v@Wv^T) stored transposed [B*1024, 2048] bf16
//   3. attn: flash attention, S^T/O^T, QBLK=128, KBLK=64, dbuf K/V.
//            R9: PV pipelined one tile behind (T15) with RACE-FREE schedule:
//            {QK(t), vf(t-1) reads, PV(t-1)} | barrier | {prefetch(t+1),
//            softmax(t), pack} | barrier. R8's single-barrier version let
//            wave A's prefetch overwrite buf[cur^1] while wave B still read
//            V(t-1) from it (absmax 1.9e-2). Barrier #1 closes that window;
//            prefetch now hides under softmax+pack instead of PV.
//   4. gemm_out: out = Xp @ Wo^T (fp32), BK=64 + C^T epilogue -> float4.

#define DEV __device__ __forceinline__

typedef __bf16 bf16x8 __attribute__((ext_vector_type(8)));
typedef __bf16 bf16x2 __attribute__((ext_vector_type(2)));
typedef float f32x4 __attribute__((ext_vector_type(4)));
typedef unsigned int u32x2 __attribute__((ext_vector_type(2)));

typedef __attribute__((address_space(1))) const unsigned int g_u32;
typedef __attribute__((address_space(3))) unsigned int l_u32;

DEV unsigned short f2bf(float x) {  // RNE truncate to bf16
  unsigned int u = __float_as_uint(x);
  u += 0x7fffu + ((u >> 16) & 1u);
  return (unsigned short)(u >> 16);
}

DEV unsigned int pack2bf(float a, float b) {
#if __has_builtin(__builtin_amdgcn_cvt_pk_bf16_f32)
  bf16x2 r = __builtin_amdgcn_cvt_pk_bf16_f32(a, b);
  union { bf16x2 v; unsigned int u; } c;
  c.v = r;
  return c.u;
#else
  unsigned int ua = __float_as_uint(a) + 0x8000u;
  unsigned int ub = __float_as_uint(b) + 0x8000u;
  return (ua >> 16) | (ub & 0xffff0000u);
#endif
}

DEV float fexp2(float x) {
#if __has_builtin(__builtin_amdgcn_exp2f)
  return __builtin_amdgcn_exp2f(x);
#else
  return __expf(x * 0.69314718056f);
#endif
}

DEV void ld16(const unsigned short* g, unsigned short* l) {
  // async global->LDS, 16B per lane; LDS dest = wave-uniform base + lane*16
  __builtin_amdgcn_global_load_lds((g_u32*)g, (l_u32*)l, 16, 0, 0);
}

// One launch for all 7 casts. Blocks 0..24575: q,k,v (8192 blocks each,
// 2M float4 per tensor). Blocks 24576..28671: weights (1024 blocks each).
__global__ __launch_bounds__(256) void cast_all(
    const float* __restrict__ q, const float* __restrict__ k,
    const float* __restrict__ v, const float* __restrict__ w0,
    const float* __restrict__ w1, const float* __restrict__ w2,
    const float* __restrict__ w3, unsigned short* __restrict__ qb,
    unsigned short* __restrict__ kb, unsigned short* __restrict__ vb,
    unsigned short* __restrict__ o0, unsigned short* __restrict__ o1,
    unsigned short* __restrict__ o2, unsigned short* __restrict__ o3) {
  const int bb = blockIdx.x;
  const float* src;
  unsigned short* dst;
  int i;
  if (bb < 24576) {
    const int z = bb >> 13, lb = bb & 8191;
    src = (z == 0) ? q : (z == 1) ? k : v;
    dst = (z == 0) ? qb : (z == 1) ? kb : vb;
    i = lb * 256 + threadIdx.x;
  } else {
    const int t = bb - 24576;
    const int z = t >> 10, lb = t & 1023;
    src = (z == 0) ? w0 : (z == 1) ? w1 : (z == 2) ? w2 : w3;
    dst = (z == 0) ? o0 : (z == 1) ? o1 : (z == 2) ? o2 : o3;
    i = lb * 256 + threadIdx.x;
  }
  float4 vv = reinterpret_cast<const float4*>(src)[i];
  ushort4 o;
  o.x = f2bf(vv.x); o.y = f2bf(vv.y); o.z = f2bf(vv.z); o.w = f2bf(vv.w);
  reinterpret_cast<ushort4*>(dst)[i] = o;
}

// ---- NT GEMM core, BK=64: C[128x128] tile, A [M,1024] bf16 rm, W [N,1024].
// 4 waves, each 64x64 (4x4 MFMA tiles of 16x16x32 bf16). 32 MFMA per barrier
// pair. LDS tiles 128x64 (row stride 128B) with XOR granule swizzle
// (phys_granule = logical ^ (row&7)) -> conflict-free b128 reads.
// SW=true computes C^T (mfma(bF,aF)) -> acc[j][i], lane holds 4 consecutive
// output cols of one row; SW=false computes C -> acc[i][j] (m97 layout).
template <bool SW>
DEV void gemm_core(const unsigned short* __restrict__ A,
                   const unsigned short* __restrict__ W,
                   unsigned short* As, unsigned short* Bs,
                   f32x4 (&acc)[4][4], int tileM, int tileN) {
  const int tid = threadIdx.x;
  const int w = tid >> 6, lane = tid & 63;
  const int wr = (w & 1) * 64, wc = (w >> 1) * 64;
  const int l15 = lane & 15, g4 = lane >> 4, l7 = l15 & 7;
  const int rsub = lane >> 3;            // row within 8-row staging chunk
  const int gsrc = (lane & 7) ^ rsub;    // swizzled source granule (8 shorts)

  const f32x4 fzero = {0.f, 0.f, 0.f, 0.f};
#pragma unroll
  for (int i = 0; i < 4; i++)
#pragma unroll
    for (int j = 0; j < 4; j++) acc[i][j] = fzero;

  for (int k0 = 0; k0 < 1024; k0 += 64) {
#pragma unroll
    for (int j = 0; j < 4; ++j) {
      const int c = w * 4 + j;  // chunk: 8 rows x 128B = 1KB
      ld16(A + (size_t)(tileM + c * 8 + rsub) * 1024 + k0 + gsrc * 8, As + c * 512);
      ld16(W + (size_t)(tileN + c * 8 + rsub) * 1024 + k0 + gsrc * 8, Bs + c * 512);
    }
    __syncthreads();
#pragma unroll
    for (int kc = 0; kc < 2; kc++) {
      const int ph = ((kc * 4 + g4) ^ l7) * 8;
      bf16x8 aF[4], bF[4];
#pragma unroll
      for (int i = 0; i < 4; i++)
        aF[i] = *reinterpret_cast<const bf16x8*>(&As[(wr + i * 16 + l15) * 64 + ph]);
#pragma unroll
      for (int j = 0; j < 4; j++)
        bF[j] = *reinterpret_cast<const bf16x8*>(&Bs[(wc + j * 16 + l15) * 64 + ph]);
#pragma unroll
      for (int i = 0; i < 4; i++)
#pragma unroll
        for (int j = 0; j < 4; j++) {
          if (SW)
            acc[j][i] = __builtin_amdgcn_mfma_f32_16x16x32_bf16(bF[j], aF[i], acc[j][i], 0, 0, 0);
          else
            acc[i][j] = __builtin_amdgcn_mfma_f32_16x16x32_bf16(aF[i], bF[j], acc[i][j], 0, 0, 0);
        }
    }
    __syncthreads();
  }
}

__global__ __launch_bounds__(256) void gemm_qkv(
    const unsigned short* __restrict__ qb, const unsigned short* __restrict__ kb,
    const unsigned short* __restrict__ vb, const unsigned short* __restrict__ Wq,
    const unsigned short* __restrict__ Wk, const unsigned short* __restrict__ Wv,
    unsigned short* __restrict__ Qp, unsigned short* __restrict__ Kp,
    unsigned short* __restrict__ VpT) {
  __shared__ __align__(16) unsigned short As[128 * 64];
  __shared__ __align__(16) unsigned short Bs[128 * 64];
  const int z = blockIdx.z;
  const int tileM = blockIdx.x * 128, tileN = blockIdx.y * 128;
  const int tid = threadIdx.x, w = tid >> 6, lane = tid & 63;
  const int wr = (w & 1) * 64, wc = (w >> 1) * 64;
  const int l15 = lane & 15, g4 = lane >> 4;
  f32x4 acc[4][4];

  if (z < 2) {
    // C^T core: lane holds row tileM+wr+i*16+l15, cols +wc+j*16+g4*4+(0..3)
    gemm_core<true>((z == 0) ? qb : kb, (z == 0) ? Wq : Wk, As, Bs, acc, tileM, tileN);
    // fold score scale 1/8 AND log2(e) into Q (exp2-domain softmax downstream)
    const float qs = (z == 0) ? 0.125f * 1.44269504089f : 1.0f;
    unsigned short* C = (z == 0) ? Qp : Kp;
#pragma unroll
    for (int i = 0; i < 4; i++) {
      const size_t row = (size_t)(tileM + wr + i * 16 + l15);
#pragma unroll
      for (int j = 0; j < 4; j++) {
        const int col = tileN + wc + j * 16 + g4 * 4;
        ushort4 pk;
        pk.x = f2bf(acc[j][i][0] * qs); pk.y = f2bf(acc[j][i][1] * qs);
        pk.z = f2bf(acc[j][i][2] * qs); pk.w = f2bf(acc[j][i][3] * qs);
        *reinterpret_cast<ushort4*>(&C[row * 1024 + col]) = pk;
      }
    }
  } else {
    gemm_core<false>(vb, Wv, As, Bs, acc, tileM, tileN);
    // transposed store: VpT[(b*1024 + col)*2048 + s], 4 contiguous s per lane
    const int b = tileM / 2048, s0 = tileM % 2048;
#pragma unroll
    for (int i = 0; i < 4; i++)
#pragma unroll
      for (int j = 0; j < 4; j++) {
        int col = tileN + wc + j * 16 + l15;
        int s = s0 + wr + i * 16 + g4 * 4;
        ushort4 pk;
        pk.x = f2bf(acc[i][j][0]); pk.y = f2bf(acc[i][j][1]);
        pk.z = f2bf(acc[i][j][2]); pk.w = f2bf(acc[i][j][3]);
        *reinterpret_cast<ushort4*>(&VpT[(size_t)(b * 1024 + col) * 2048 + s]) = pk;
      }
  }
}

__global__ __launch_bounds__(256) void gemm_out(
    const unsigned short* __restrict__ Xp, const unsigned short* __restrict__ Wo,
    float* __restrict__ out) {
  __shared__ __align__(16) unsigned short As[128 * 64];
  __shared__ __align__(16) unsigned short Bs[128 * 64];
  const int tileM = blockIdx.x * 128, tileN = blockIdx.y * 128;
  f32x4 acc[4][4];
  gemm_core<true>(Xp, Wo, As, Bs, acc, tileM, tileN);
  const int tid = threadIdx.x, w = tid >> 6, lane = tid & 63;
  const int wr = (w & 1) * 64, wc = (w >> 1) * 64;
  const int l15 = lane & 15, g4 = lane >> 4;
#pragma unroll
  for (int i = 0; i < 4; i++) {
    const size_t row = (size_t)(tileM + wr + i * 16 + l15);
#pragma unroll
    for (int j = 0; j < 4; j++) {
      const int col = tileN + wc + j * 16 + g4 * 4;
      *reinterpret_cast<f32x4*>(&out[row * 1024 + col]) = acc[j][i];
    }
  }
}

// ---- Flash attention, S^T/O^T, no-max softmax, QBLK=128, dbuf K/V.
// R9 race-free T15 schedule, per tile t:
//   interval 1: QK(t) [buf cur] + vf(t-1) reads [buf cur^1] + PV(t-1)
//   barrier #1 (no drains pending -> cheap; closes buf[cur^1] read window)
//   interval 2: prefetch(t+1) -> buf[cur^1]; softmax(t); pack P(t); pf regs
//   barrier #2 (implicit vmcnt(0) drains prefetch)
__global__ __launch_bounds__(256, 4) void attn(
    const unsigned short* __restrict__ Qp, const unsigned short* __restrict__ Kp,
    const unsigned short* __restrict__ VpT, unsigned short* __restrict__ Xp) {
  __shared__ __align__(16) unsigned short Ks[2 * 64 * 64];  // [buf][kp][d], 16B-gran swz
  __shared__ __align__(16) unsigned short Vs[2 * 64 * 64];  // [buf][d][kp], 16B-gran swz
  __shared__ __align__(16) unsigned short Ps[4 * 16 * 64];  // per-wave P[m][kp], 8B swz

  const int bid = blockIdx.x;
  const int nid = (bid & 7) * 128 + (bid >> 3);  // bijective, 1024%8==0
  const int qt = nid & 15, bh = nid >> 4;
  const int b = bh >> 4, h = bh & 15;
  const int q0 = qt * 128;
  const int tid = threadIdx.x, w = tid >> 6, lane = tid & 63;
  const int l15 = lane & 15, g4 = lane >> 4;
  const int l7 = l15 & 7;

  const int rsub = lane >> 3;
  const int gsrc = (lane & 7) ^ rsub;

  bf16x8 qf[2][2];
#pragma unroll
  for (int mi = 0; mi < 2; mi++) {
    const unsigned short* Qrow =
        Qp + (size_t)(b * 2048 + q0 + w * 32 + mi * 16 + l15) * 1024 + h * 64;
    qf[mi][0] = *reinterpret_cast<const bf16x8*>(Qrow + g4 * 8);
    qf[mi][1] = *reinterpret_cast<const bf16x8*>(Qrow + 32 + g4 * 8);
  }

  const f32x4 fzero = {0.f, 0.f, 0.f, 0.f};
  f32x4 o[2][4];
#pragma unroll
  for (int mi = 0; mi < 2; mi++)
#pragma unroll
    for (int dj = 0; dj < 4; dj++) o[mi][dj] = fzero;
  float l_i[2] = {0.f, 0.f};  // per-lane partial denominators

  const unsigned short* Kbase = Kp + (size_t)(b * 2048) * 1024 + h * 64;
  const unsigned short* Vbase = VpT + (size_t)(b * 1024 + h * 64) * 2048;
  unsigned short* Pw = Ps + w * 1024;

  const int c = w * 2;  // this wave's two staging chunks are c, c+1

  // P fragments of the previous tile, carried in registers (mi, kc)
  u32x2 pfa[2][2], pfb[2][2];

  // prologue: stage tile 0 into buffer 0
#pragma unroll
  for (int j = 0; j < 2; ++j) {
    ld16(Kbase + (size_t)((c + j) * 8 + rsub) * 1024 + gsrc * 8, Ks + (c + j) * 512);
    ld16(Vbase + (size_t)((c + j) * 8 + rsub) * 2048 + gsrc * 8, Vs + (c + j) * 512);
  }
  __syncthreads();  // implicit vmcnt(0): tile 0 resident

  // ---- peel t=0: prefetch(1) -> buf1 (nobody reads buf1 this interval),
  // QK(0), softmax(0), pack, pf capture. Single drain barrier.
  {
#pragma unroll
    for (int j = 0; j < 2; ++j) {
      ld16(Kbase + (size_t)(64 + (c + j) * 8 + rsub) * 1024 + gsrc * 8,
           Ks + 4096 + (c + j) * 512);
      ld16(Vbase + (size_t)((c + j) * 8 + rsub) * 2048 + 64 + gsrc * 8,
           Vs + 4096 + (c + j) * 512);
    }
    f32x4 sv[2][4];
    __builtin_amdgcn_s_setprio(1);
#pragma unroll
    for (int jt = 0; jt < 4; jt++) {
      const int row = jt * 16 + l15;
      const int s0 = g4 ^ l7;
      bf16x8 kf0 = *reinterpret_cast<const bf16x8*>(&Ks[row * 64 + s0 * 8]);
      bf16x8 kf1 = *reinterpret_cast<const bf16x8*>(&Ks[row * 64 + (s0 ^ 4) * 8]);
#pragma unroll
      for (int mi = 0; mi < 2; mi++) {
        f32x4 z = fzero;
        z = __builtin_amdgcn_mfma_f32_16x16x32_bf16(kf0, qf[mi][0], z, 0, 0, 0);
        z = __builtin_amdgcn_mfma_f32_16x16x32_bf16(kf1, qf[mi][1], z, 0, 0, 0);
        sv[mi][jt] = z;
      }
    }
    __builtin_amdgcn_s_setprio(0);
#pragma unroll
    for (int mi = 0; mi < 2; mi++) {
      float rs = 0.f;
#pragma unroll
      for (int jt = 0; jt < 4; jt++)
#pragma unroll
        for (int r = 0; r < 4; r++) {
          sv[mi][jt][r] = fexp2(sv[mi][jt][r]);
          rs += sv[mi][jt][r];
        }
      l_i[mi] += rs;
    }
#pragma unroll
    for (int mi = 0; mi < 2; mi++) {
#pragma unroll
      for (int jt = 0; jt < 4; jt++) {
        u32x2 pk;
        pk.x = pack2bf(sv[mi][jt][0], sv[mi][jt][1]);
        pk.y = pack2bf(sv[mi][jt][2], sv[mi][jt][3]);
        const int slot = (jt * 4 + g4) ^ l15;
        *reinterpret_cast<u32x2*>(&Pw[l15 * 64 + slot * 4]) = pk;
      }
#pragma unroll
      for (int kc = 0; kc < 2; kc++) {
        const int sA = (kc * 8 + g4 * 2) ^ l15;
        const int sB = (kc * 8 + g4 * 2 + 1) ^ l15;
        pfa[mi][kc] = *reinterpret_cast<const u32x2*>(&Pw[l15 * 64 + sA * 4]);
        pfb[mi][kc] = *reinterpret_cast<const u32x2*>(&Pw[l15 * 64 + sB * 4]);
      }
    }
    __syncthreads();  // drains prefetch(1)
  }

  int cur = 1;
  for (int t = 1; t < 32; ++t) {
    unsigned short* Kc = Ks + cur * 4096;
    unsigned short* Vp = Vs + (cur ^ 1) * 4096;  // V of tile t-1

    // ---- interval 1: QK(t) + vf(t-1) + PV(t-1) (all reads of both bufs)
    f32x4 sv[2][4];
    __builtin_amdgcn_s_setprio(1);
#pragma unroll
    for (int jt = 0; jt < 4; jt++) {
      const int row = jt * 16 + l15;
      const int s0 = g4 ^ l7;
      bf16x8 kf0 = *reinterpret_cast<const bf16x8*>(&Kc[row * 64 + s0 * 8]);
      bf16x8 kf1 = *reinterpret_cast<const bf16x8*>(&Kc[row * 64 + (s0 ^ 4) * 8]);
#pragma unroll
      for (int mi = 0; mi < 2; mi++) {
        f32x4 z = fzero;
        z = __builtin_amdgcn_mfma_f32_16x16x32_bf16(kf0, qf[mi][0], z, 0, 0, 0);
        z = __builtin_amdgcn_mfma_f32_16x16x32_bf16(kf1, qf[mi][1], z, 0, 0, 0);
        sv[mi][jt] = z;
      }
    }

    bf16x8 vf[2][4];
#pragma unroll
    for (int kc = 0; kc < 2; kc++)
#pragma unroll
      for (int dj = 0; dj < 4; dj++)
        vf[kc][dj] = *reinterpret_cast<const bf16x8*>(
            &Vp[(dj * 16 + l15) * 64 + ((kc * 4 + g4) ^ l7) * 8]);

    // PV(t-1): results not consumed until next tile -> drains under softmax
#pragma unroll
    for (int mi = 0; mi < 2; mi++)
#pragma unroll
      for (int kc = 0; kc < 2; kc++) {
        union { unsigned int u[4]; bf16x8 v; } pf;
        pf.u[0] = pfa[mi][kc].x; pf.u[1] = pfa[mi][kc].y;
        pf.u[2] = pfb[mi][kc].x; pf.u[3] = pfb[mi][kc].y;
#pragma unroll
        for (int dj = 0; dj < 4; dj++)
          o[mi][dj] = __builtin_amdgcn_mfma_f32_16x16x32_bf16(vf[kc][dj], pf.v,
                                                             o[mi][dj], 0, 0, 0);
      }
    __builtin_amdgcn_s_setprio(0);

    // barrier #1: ALL waves done reading buf[cur^1] (vmcnt already 0 ->
    // cheap sync, no drain). Closes R8's cross-wave prefetch/read race.
    __syncthreads();

    // ---- interval 2: prefetch(t+1) hidden under softmax+pack
    if (t < 31) {
      unsigned short* Kn = Ks + (cur ^ 1) * 4096;
      unsigned short* Vn = Vs + (cur ^ 1) * 4096;
      const int ktn = (t + 1) * 64;
#pragma unroll
      for (int j = 0; j < 2; ++j) {
        ld16(Kbase + (size_t)(ktn + (c + j) * 8 + rsub) * 1024 + gsrc * 8,
             Kn + (c + j) * 512);
        ld16(Vbase + (size_t)((c + j) * 8 + rsub) * 2048 + ktn + gsrc * 8,
             Vn + (c + j) * 512);
      }
    }

    // softmax(t): exp2 + per-lane denominator
#pragma unroll
    for (int mi = 0; mi < 2; mi++) {
      float rs = 0.f;
#pragma unroll
      for (int jt = 0; jt < 4; jt++)
#pragma unroll
        for (int r = 0; r < 4; r++) {
          sv[mi][jt][r] = fexp2(sv[mi][jt][r]);
          rs += sv[mi][jt][r];
        }
      l_i[mi] += rs;
    }

    // pack P(t) -> Pw (per-wave region), capture pf regs for next PV
#pragma unroll
    for (int mi = 0; mi < 2; mi++) {
#pragma unroll
      for (int jt = 0; jt < 4; jt++) {
        u32x2 pk;
        pk.x = pack2bf(sv[mi][jt][0], sv[mi][jt][1]);
        pk.y = pack2bf(sv[mi][jt][2], sv[mi][jt][3]);
        const int slot = (jt * 4 + g4) ^ l15;
        *reinterpret_cast<u32x2*>(&Pw[l15 * 64 + slot * 4]) = pk;
      }
#pragma unroll
      for (int kc = 0; kc < 2; kc++) {
        const int sA = (kc * 8 + g4 * 2) ^ l15;
        const int sB = (kc * 8 + g4 * 2 + 1) ^ l15;
        pfa[mi][kc] = *reinterpret_cast<const u32x2*>(&Pw[l15 * 64 + sA * 4]);
        pfb[mi][kc] = *reinterpret_cast<const u32x2*>(&Pw[l15 * 64 + sB * 4]);
      }
    }

    __syncthreads();  // barrier #2: drains prefetch; buf[cur^1] now tile t+1
    cur ^= 1;
  }

  // ---- epilogue PV(31): after final flip, V(31) is in buf[cur^1]
  {
    unsigned short* Vp = Vs + (cur ^ 1) * 4096;
    bf16x8 vf[2][4];
#pragma unroll
    for (int kc = 0; kc < 2; kc++)
#pragma unroll
      for (int dj = 0; dj < 4; dj++)
        vf[kc][dj] = *reinterpret_cast<const bf16x8*>(
            &Vp[(dj * 16 + l15) * 64 + ((kc * 4 + g4) ^ l7) * 8]);
#pragma unroll
    for (int mi = 0; mi < 2; mi++)
#pragma unroll
      for (int kc = 0; kc < 2; kc++) {
        union { unsigned int u[4]; bf16x8 v; } pf;
        pf.u[0] = pfa[mi][kc].x; pf.u[1] = pfa[mi][kc].y;
        pf.u[2] = pfb[mi][kc].x; pf.u[3] = pfb[mi][kc].y;
#pragma unroll
        for (int dj = 0; dj < 4; dj++)
          o[mi][dj] = __builtin_amdgcn_mfma_f32_16x16x32_bf16(vf[kc][dj], pf.v,
                                                             o[mi][dj], 0, 0, 0);
      }
  }

  // epilogue: reduce denominator over the 4 g4 groups, then store O^T
#pragma unroll
  for (int mi = 0; mi < 2; mi++) {
    float rs = l_i[mi];
    rs += __shfl_xor(rs, 16);
    rs += __shfl_xor(rs, 32);
    const float inv = 1.f / rs;
    const size_t row = (size_t)(b * 2048 + q0 + w * 32 + mi * 16 + l15);
#pragma unroll
    for (int dj = 0; dj < 4; dj++) {
      ushort4 pk;
      pk.x = f2bf(o[mi][dj][0] * inv);
      pk.y = f2bf(o[mi][dj][1] * inv);
      pk.z = f2bf(o[mi][dj][2] * inv);
      pk.w = f2bf(o[mi][dj][3] * inv);
      *reinterpret_cast<ushort4*>(&Xp[row * 1024 + h * 64 + dj * 16 + g4 * 4]) = pk;
    }
  }
}

extern "C" void kernel_launch(void* const* d_in, const int* in_sizes, int n_in,
                              void* d_out, int out_size, void* d_ws, size_t ws_size,
                              hipStream_t stream) {
  const float* q  = (const float*)d_in[0];
  const float* k  = (const float*)d_in[1];
  const float* v  = (const float*)d_in[2];
  // d_in[3] mask: unused by the reference
  const float* Wq = (const float*)d_in[4];
  const float* Wk = (const float*)d_in[5];
  const float* Wv = (const float*)d_in[6];
  const float* Wo = (const float*)d_in[7];
  float* out = (float*)d_out;

  char* ws = (char*)d_ws;
  const size_t MB = 1u << 20;
  unsigned short* qb  = (unsigned short*)(ws + 0 * MB);    // 16 MB each
  unsigned short* kb  = (unsigned short*)(ws + 16 * MB);
  unsigned short* vb  = (unsigned short*)(ws + 32 * MB);
  unsigned short* wqb = (unsigned short*)(ws + 48 * MB);   // 2 MB each
  unsigned short* wkb = (unsigned short*)(ws + 50 * MB);
  unsigned short* wvb = (unsigned short*)(ws + 52 * MB);
  unsigned short* wob = (unsigned short*)(ws + 54 * MB);
  unsigned short* Qp  = (unsigned short*)(ws + 56 * MB);   // 16 MB (pre-scaled)
  unsigned short* Kp  = (unsigned short*)(ws + 72 * MB);   // 16 MB
  unsigned short* VpT = (unsigned short*)(ws + 88 * MB);   // 16 MB, [B*1024, 2048]
  unsigned short* Xp  = (unsigned short*)(ws + 104 * MB);  // 16 MB

  // 3*8192 blocks (q,k,v) + 4*1024 blocks (weights) = 28672
  cast_all<<<dim3(28672), 256, 0, stream>>>(q, k, v, Wq, Wk, Wv, Wo,
                                            qb, kb, vb, wqb, wkb, wvb, wob);

  dim3 gq(64, 8, 3);
  gemm_qkv<<<gq, 256, 0, stream>>>(qb, kb, vb, wqb, wkb, wvb, Qp, Kp, VpT);

  attn<<<dim3(1024), 256, 0, stream>>>(Qp, Kp, VpT, Xp);

  dim3 go(64, 8, 1);
  gemm_out<<<go, 256, 0, stream>>>(Xp, wob, out);
}

// Round 10
// 355.362 us; speedup vs baseline: 1.3877x; 1.0099x over previous
//
#include <hip/hip_runtime.h>
#include <math.h>

// Problem: B=4, S=2048, D=1024, H=16, DK=64.
// out = softmax((q Wq^T)(k Wk^T)^T / 8) (v Wv^T) Wo^T, heads split on D.
//
// Pipeline:
//   1. cast_all: fp32->bf16 for {q,k,v,Wq,Wk,Wv,Wo} in ONE launch
//   2. gemm_qkv: Qp=(q@Wq^T)*(0.125*log2e), Kp=k@Wk^T (bf16 [8192,1024]),
//                VpT = (v@Wv^T) stored transposed [B*1024, 2048] bf16
//   3. attn: flash attention, S^T/O^T, QBLK=256 (R10: doubled from 128 --
//            K/V staged once per 256 q-rows -> L2 staging traffic halves,
//            64 MFMA per barrier interval per wave; R4 proved AI dominates
//            occupancy for this kernel). R5-proven single-barrier dbuf
//            schedule (no cross-buffer reads -> no R8 race class).
//   4. gemm_out: out = Xp @ Wo^T (fp32), BK=64 + C^T epilogue -> float4.

#define DEV __device__ __forceinline__

typedef __bf16 bf16x8 __attribute__((ext_vector_type(8)));
typedef __bf16 bf16x2 __attribute__((ext_vector_type(2)));
typedef float f32x4 __attribute__((ext_vector_type(4)));
typedef unsigned int u32x2 __attribute__((ext_vector_type(2)));

typedef __attribute__((address_space(1))) const unsigned int g_u32;
typedef __attribute__((address_space(3))) unsigned int l_u32;

DEV unsigned short f2bf(float x) {  // RNE truncate to bf16
  unsigned int u = __float_as_uint(x);
  u += 0x7fffu + ((u >> 16) & 1u);
  return (unsigned short)(u >> 16);
}

DEV unsigned int pack2bf(float a, float b) {
#if __has_builtin(__builtin_amdgcn_cvt_pk_bf16_f32)
  bf16x2 r = __builtin_amdgcn_cvt_pk_bf16_f32(a, b);
  union { bf16x2 v; unsigned int u; } c;
  c.v = r;
  return c.u;
#else
  unsigned int ua = __float_as_uint(a) + 0x8000u;
  unsigned int ub = __float_as_uint(b) + 0x8000u;
  return (ua >> 16) | (ub & 0xffff0000u);
#endif
}

DEV float fexp2(float x) {
#if __has_builtin(__builtin_amdgcn_exp2f)
  return __builtin_amdgcn_exp2f(x);
#else
  return __expf(x * 0.69314718056f);
#endif
}

DEV void ld16(const unsigned short* g, unsigned short* l) {
  // async global->LDS, 16B per lane; LDS dest = wave-uniform base + lane*16
  __builtin_amdgcn_global_load_lds((g_u32*)g, (l_u32*)l, 16, 0, 0);
}

// One launch for all 7 casts. Blocks 0..24575: q,k,v (8192 blocks each,
// 2M float4 per tensor). Blocks 24576..28671: weights (1024 blocks each).
__global__ __launch_bounds__(256) void cast_all(
    const float* __restrict__ q, const float* __restrict__ k,
    const float* __restrict__ v, const float* __restrict__ w0,
    const float* __restrict__ w1, const float* __restrict__ w2,
    const float* __restrict__ w3, unsigned short* __restrict__ qb,
    unsigned short* __restrict__ kb, unsigned short* __restrict__ vb,
    unsigned short* __restrict__ o0, unsigned short* __restrict__ o1,
    unsigned short* __restrict__ o2, unsigned short* __restrict__ o3) {
  const int bb = blockIdx.x;
  const float* src;
  unsigned short* dst;
  int i;
  if (bb < 24576) {
    const int z = bb >> 13, lb = bb & 8191;
    src = (z == 0) ? q : (z == 1) ? k : v;
    dst = (z == 0) ? qb : (z == 1) ? kb : vb;
    i = lb * 256 + threadIdx.x;
  } else {
    const int t = bb - 24576;
    const int z = t >> 10, lb = t & 1023;
    src = (z == 0) ? w0 : (z == 1) ? w1 : (z == 2) ? w2 : w3;
    dst = (z == 0) ? o0 : (z == 1) ? o1 : (z == 2) ? o2 : o3;
    i = lb * 256 + threadIdx.x;
  }
  float4 vv = reinterpret_cast<const float4*>(src)[i];
  ushort4 o;
  o.x = f2bf(vv.x); o.y = f2bf(vv.y); o.z = f2bf(vv.z); o.w = f2bf(vv.w);
  reinterpret_cast<ushort4*>(dst)[i] = o;
}

// ---- NT GEMM core, BK=64: C[128x128] tile, A [M,1024] bf16 rm, W [N,1024].
// 4 waves, each 64x64 (4x4 MFMA tiles of 16x16x32 bf16). 32 MFMA per barrier
// pair. LDS tiles 128x64 (row stride 128B) with XOR granule swizzle
// (phys_granule = logical ^ (row&7)) -> conflict-free b128 reads.
// SW=true computes C^T (mfma(bF,aF)) -> acc[j][i], lane holds 4 consecutive
// output cols of one row; SW=false computes C -> acc[i][j] (m97 layout).
template <bool SW>
DEV void gemm_core(const unsigned short* __restrict__ A,
                   const unsigned short* __restrict__ W,
                   unsigned short* As, unsigned short* Bs,
                   f32x4 (&acc)[4][4], int tileM, int tileN) {
  const int tid = threadIdx.x;
  const int w = tid >> 6, lane = tid & 63;
  const int wr = (w & 1) * 64, wc = (w >> 1) * 64;
  const int l15 = lane & 15, g4 = lane >> 4, l7 = l15 & 7;
  const int rsub = lane >> 3;            // row within 8-row staging chunk
  const int gsrc = (lane & 7) ^ rsub;    // swizzled source granule (8 shorts)

  const f32x4 fzero = {0.f, 0.f, 0.f, 0.f};
#pragma unroll
  for (int i = 0; i < 4; i++)
#pragma unroll
    for (int j = 0; j < 4; j++) acc[i][j] = fzero;

  for (int k0 = 0; k0 < 1024; k0 += 64) {
#pragma unroll
    for (int j = 0; j < 4; ++j) {
      const int c = w * 4 + j;  // chunk: 8 rows x 128B = 1KB
      ld16(A + (size_t)(tileM + c * 8 + rsub) * 1024 + k0 + gsrc * 8, As + c * 512);
      ld16(W + (size_t)(tileN + c * 8 + rsub) * 1024 + k0 + gsrc * 8, Bs + c * 512);
    }
    __syncthreads();
#pragma unroll
    for (int kc = 0; kc < 2; kc++) {
      const int ph = ((kc * 4 + g4) ^ l7) * 8;
      bf16x8 aF[4], bF[4];
#pragma unroll
      for (int i = 0; i < 4; i++)
        aF[i] = *reinterpret_cast<const bf16x8*>(&As[(wr + i * 16 + l15) * 64 + ph]);
#pragma unroll
      for (int j = 0; j < 4; j++)
        bF[j] = *reinterpret_cast<const bf16x8*>(&Bs[(wc + j * 16 + l15) * 64 + ph]);
#pragma unroll
      for (int i = 0; i < 4; i++)
#pragma unroll
        for (int j = 0; j < 4; j++) {
          if (SW)
            acc[j][i] = __builtin_amdgcn_mfma_f32_16x16x32_bf16(bF[j], aF[i], acc[j][i], 0, 0, 0);
          else
            acc[i][j] = __builtin_amdgcn_mfma_f32_16x16x32_bf16(aF[i], bF[j], acc[i][j], 0, 0, 0);
        }
    }
    __syncthreads();
  }
}

__global__ __launch_bounds__(256) void gemm_qkv(
    const unsigned short* __restrict__ qb, const unsigned short* __restrict__ kb,
    const unsigned short* __restrict__ vb, const unsigned short* __restrict__ Wq,
    const unsigned short* __restrict__ Wk, const unsigned short* __restrict__ Wv,
    unsigned short* __restrict__ Qp, unsigned short* __restrict__ Kp,
    unsigned short* __restrict__ VpT) {
  __shared__ __align__(16) unsigned short As[128 * 64];
  __shared__ __align__(16) unsigned short Bs[128 * 64];
  const int z = blockIdx.z;
  const int tileM = blockIdx.x * 128, tileN = blockIdx.y * 128;
  const int tid = threadIdx.x, w = tid >> 6, lane = tid & 63;
  const int wr = (w & 1) * 64, wc = (w >> 1) * 64;
  const int l15 = lane & 15, g4 = lane >> 4;
  f32x4 acc[4][4];

  if (z < 2) {
    // C^T core: lane holds row tileM+wr+i*16+l15, cols +wc+j*16+g4*4+(0..3)
    gemm_core<true>((z == 0) ? qb : kb, (z == 0) ? Wq : Wk, As, Bs, acc, tileM, tileN);
    // fold score scale 1/8 AND log2(e) into Q (exp2-domain softmax downstream)
    const float qs = (z == 0) ? 0.125f * 1.44269504089f : 1.0f;
    unsigned short* C = (z == 0) ? Qp : Kp;
#pragma unroll
    for (int i = 0; i < 4; i++) {
      const size_t row = (size_t)(tileM + wr + i * 16 + l15);
#pragma unroll
      for (int j = 0; j < 4; j++) {
        const int col = tileN + wc + j * 16 + g4 * 4;
        ushort4 pk;
        pk.x = f2bf(acc[j][i][0] * qs); pk.y = f2bf(acc[j][i][1] * qs);
        pk.z = f2bf(acc[j][i][2] * qs); pk.w = f2bf(acc[j][i][3] * qs);
        *reinterpret_cast<ushort4*>(&C[row * 1024 + col]) = pk;
      }
    }
  } else {
    gemm_core<false>(vb, Wv, As, Bs, acc, tileM, tileN);
    // transposed store: VpT[(b*1024 + col)*2048 + s], 4 contiguous s per lane
    const int b = tileM / 2048, s0 = tileM % 2048;
#pragma unroll
    for (int i = 0; i < 4; i++)
#pragma unroll
      for (int j = 0; j < 4; j++) {
        int col = tileN + wc + j * 16 + l15;
        int s = s0 + wr + i * 16 + g4 * 4;
        ushort4 pk;
        pk.x = f2bf(acc[i][j][0]); pk.y = f2bf(acc[i][j][1]);
        pk.z = f2bf(acc[i][j][2]); pk.w = f2bf(acc[i][j][3]);
        *reinterpret_cast<ushort4*>(&VpT[(size_t)(b * 1024 + col) * 2048 + s]) = pk;
      }
  }
}

__global__ __launch_bounds__(256) void gemm_out(
    const unsigned short* __restrict__ Xp, const unsigned short* __restrict__ Wo,
    float* __restrict__ out) {
  __shared__ __align__(16) unsigned short As[128 * 64];
  __shared__ __align__(16) unsigned short Bs[128 * 64];
  const int tileM = blockIdx.x * 128, tileN = blockIdx.y * 128;
  f32x4 acc[4][4];
  gemm_core<true>(Xp, Wo, As, Bs, acc, tileM, tileN);
  const int tid = threadIdx.x, w = tid >> 6, lane = tid & 63;
  const int wr = (w & 1) * 64, wc = (w >> 1) * 64;
  const int l15 = lane & 15, g4 = lane >> 4;
#pragma unroll
  for (int i = 0; i < 4; i++) {
    const size_t row = (size_t)(tileM + wr + i * 16 + l15);
#pragma unroll
    for (int j = 0; j < 4; j++) {
      const int col = tileN + wc + j * 16 + g4 * 4;
      *reinterpret_cast<f32x4*>(&out[row * 1024 + col]) = acc[j][i];
    }
  }
}

// ---- Flash attention, S^T/O^T, no-max softmax, QBLK=256, KBLK=64.
// R10: each wave owns 64 q-rows (mi=0..3). Per tile t (R5-proven schedule):
//   stage(t+1)->buf^1 ; QK(all mi) ; exp2(all mi) ; pack(all mi)->Ps ;
//   vf read ; PV(all mi) ; ONE barrier (drains stage, closes buf reads).
// sv dies at pack (before vf) -> peak VGPR ~184. Ps = 4 waves x 4 mi x 2KB
// = 32KB; LDS total 64KB -> 2 blocks/CU = exactly the 512-block grid / 256.
// XCD swizzle: nid=(bid&7)*64+bid>>3 -> 8 (b,h) panels per XCD (4MB = L2).
__global__ __launch_bounds__(256, 2) void attn(
    const unsigned short* __restrict__ Qp, const unsigned short* __restrict__ Kp,
    const unsigned short* __restrict__ VpT, unsigned short* __restrict__ Xp) {
  __shared__ __align__(16) unsigned short Ks[2 * 64 * 64];   // [buf][kp][d]
  __shared__ __align__(16) unsigned short Vs[2 * 64 * 64];   // [buf][d][kp]
  __shared__ __align__(16) unsigned short Ps[4 * 4 * 1024];  // [wave][mi][16x64]

  const int bid = blockIdx.x;
  const int nid = (bid & 7) * 64 + (bid >> 3);  // bijective, 512%8==0
  const int qt = nid & 7, bh = nid >> 3;
  const int b = bh >> 4, h = bh & 15;
  const int q0 = qt * 256;
  const int tid = threadIdx.x, w = tid >> 6, lane = tid & 63;
  const int l15 = lane & 15, g4 = lane >> 4;
  const int l7 = l15 & 7;

  const int rsub = lane >> 3;
  const int gsrc = (lane & 7) ^ rsub;

  // Q rows: wave w owns rows q0 + w*64 + mi*16 + l15
  bf16x8 qf[4][2];
#pragma unroll
  for (int mi = 0; mi < 4; mi++) {
    const unsigned short* Qrow =
        Qp + (size_t)(b * 2048 + q0 + w * 64 + mi * 16 + l15) * 1024 + h * 64;
    qf[mi][0] = *reinterpret_cast<const bf16x8*>(Qrow + g4 * 8);
    qf[mi][1] = *reinterpret_cast<const bf16x8*>(Qrow + 32 + g4 * 8);
  }

  const f32x4 fzero = {0.f, 0.f, 0.f, 0.f};
  f32x4 o[4][4];
#pragma unroll
  for (int mi = 0; mi < 4; mi++)
#pragma unroll
    for (int dj = 0; dj < 4; dj++) o[mi][dj] = fzero;
  float l_i[4] = {0.f, 0.f, 0.f, 0.f};

  const unsigned short* Kbase = Kp + (size_t)(b * 2048) * 1024 + h * 64;
  const unsigned short* Vbase = VpT + (size_t)(b * 1024 + h * 64) * 2048;
  unsigned short* Pw = Ps + w * 4096;  // this wave's 4 mi regions

  const int c = w * 2;  // this wave's two staging chunks are c, c+1

  // prologue: stage tile 0 into buffer 0
#pragma unroll
  for (int j = 0; j < 2; ++j) {
    ld16(Kbase + (size_t)((c + j) * 8 + rsub) * 1024 + gsrc * 8, Ks + (c + j) * 512);
    ld16(Vbase + (size_t)((c + j) * 8 + rsub) * 2048 + gsrc * 8, Vs + (c + j) * 512);
  }
  __syncthreads();  // implicit vmcnt(0): tile 0 resident

  int cur = 0;
  for (int t = 0; t < 32; ++t) {
    const int kt = t * 64;
    unsigned short* Kc = Ks + cur * 4096;
    unsigned short* Vc = Vs + cur * 4096;

    // stage tile t+1 into the other buffer (flies under this tile's compute)
    if (t < 31) {
      unsigned short* Kn = Ks + (cur ^ 1) * 4096;
      unsigned short* Vn = Vs + (cur ^ 1) * 4096;
      const int ktn = kt + 64;
#pragma unroll
      for (int j = 0; j < 2; ++j) {
        ld16(Kbase + (size_t)(ktn + (c + j) * 8 + rsub) * 1024 + gsrc * 8,
             Kn + (c + j) * 512);
        ld16(Vbase + (size_t)((c + j) * 8 + rsub) * 2048 + ktn + gsrc * 8,
             Vn + (c + j) * 512);
      }
    }

    // QK: sv[mi][jt][r] = S'[m=mi*16+l15][kp = kt + jt*16 + g4*4 + r]
    f32x4 sv[4][4];
    __builtin_amdgcn_s_setprio(1);
#pragma unroll
    for (int jt = 0; jt < 4; jt++) {
      const int row = jt * 16 + l15;
      const int s0 = g4 ^ l7;
      bf16x8 kf0 = *reinterpret_cast<const bf16x8*>(&Kc[row * 64 + s0 * 8]);
      bf16x8 kf1 = *reinterpret_cast<const bf16x8*>(&Kc[row * 64 + (s0 ^ 4) * 8]);
#pragma unroll
      for (int mi = 0; mi < 4; mi++) {
        f32x4 z = fzero;
        z = __builtin_amdgcn_mfma_f32_16x16x32_bf16(kf0, qf[mi][0], z, 0, 0, 0);
        z = __builtin_amdgcn_mfma_f32_16x16x32_bf16(kf1, qf[mi][1], z, 0, 0, 0);
        sv[mi][jt] = z;
      }
    }
    __builtin_amdgcn_s_setprio(0);

    // exp2 + per-lane denominator, then pack ALL mi (sv dies here)
#pragma unroll
    for (int mi = 0; mi < 4; mi++) {
      float rs = 0.f;
#pragma unroll
      for (int jt = 0; jt < 4; jt++)
#pragma unroll
        for (int r = 0; r < 4; r++) {
          sv[mi][jt][r] = fexp2(sv[mi][jt][r]);
          rs += sv[mi][jt][r];
        }
      l_i[mi] += rs;
#pragma unroll
      for (int jt = 0; jt < 4; jt++) {
        u32x2 pk;
        pk.x = pack2bf(sv[mi][jt][0], sv[mi][jt][1]);
        pk.y = pack2bf(sv[mi][jt][2], sv[mi][jt][3]);
        const int slot = (jt * 4 + g4) ^ l15;
        *reinterpret_cast<u32x2*>(&Pw[mi * 1024 + l15 * 64 + slot * 4]) = pk;
      }
    }

    // V fragments: read once, reused for all 4 m-tiles
    bf16x8 vf[2][4];
#pragma unroll
    for (int kc = 0; kc < 2; kc++)
#pragma unroll
      for (int dj = 0; dj < 4; dj++)
        vf[kc][dj] = *reinterpret_cast<const bf16x8*>(
            &Vc[(dj * 16 + l15) * 64 + ((kc * 4 + g4) ^ l7) * 8]);

    // O^T += V^T P^T per mi (in-wave DS ordering: pack-write -> read safe)
    __builtin_amdgcn_s_setprio(1);
#pragma unroll
    for (int mi = 0; mi < 4; mi++) {
#pragma unroll
      for (int kc = 0; kc < 2; kc++) {
        const int sA = (kc * 8 + g4 * 2) ^ l15;
        const int sB = (kc * 8 + g4 * 2 + 1) ^ l15;
        u32x2 pa = *reinterpret_cast<const u32x2*>(&Pw[mi * 1024 + l15 * 64 + sA * 4]);
        u32x2 pb = *reinterpret_cast<const u32x2*>(&Pw[mi * 1024 + l15 * 64 + sB * 4]);
        union { unsigned int u[4]; bf16x8 v; } pf;
        pf.u[0] = pa.x; pf.u[1] = pa.y; pf.u[2] = pb.x; pf.u[3] = pb.y;
#pragma unroll
        for (int dj = 0; dj < 4; dj++)
          o[mi][dj] = __builtin_amdgcn_mfma_f32_16x16x32_bf16(vf[kc][dj], pf.v,
                                                             o[mi][dj], 0, 0, 0);
      }
    }
    __builtin_amdgcn_s_setprio(0);

    // ONE barrier per tile: (a) all waves done reading buf[cur] before it is
    // restaged next iter; (b) implicit vmcnt(0) drains t+1's loads, which
    // have been in flight across the whole compute phase above.
    __syncthreads();
    cur ^= 1;
  }

  // epilogue: reduce denominator over the 4 g4 groups, then store O^T
#pragma unroll
  for (int mi = 0; mi < 4; mi++) {
    float rs = l_i[mi];
    rs += __shfl_xor(rs, 16);
    rs += __shfl_xor(rs, 32);
    const float inv = 1.f / rs;
    const size_t row = (size_t)(b * 2048 + q0 + w * 64 + mi * 16 + l15);
#pragma unroll
    for (int dj = 0; dj < 4; dj++) {
      ushort4 pk;
      pk.x = f2bf(o[mi][dj][0] * inv);
      pk.y = f2bf(o[mi][dj][1] * inv);
      pk.z = f2bf(o[mi][dj][2] * inv);
      pk.w = f2bf(o[mi][dj][3] * inv);
      *reinterpret_cast<ushort4*>(&Xp[row * 1024 + h * 64 + dj * 16 + g4 * 4]) = pk;
    }
  }
}

extern "C" void kernel_launch(void* const* d_in, const int* in_sizes, int n_in,
                              void* d_out, int out_size, void* d_ws, size_t ws_size,
                              hipStream_t stream) {
  const float* q  = (const float*)d_in[0];
  const float* k  = (const float*)d_in[1];
  const float* v  = (const float*)d_in[2];
  // d_in[3] mask: unused by the reference
  const float* Wq = (const float*)d_in[4];
  const float* Wk = (const float*)d_in[5];
  const float* Wv = (const float*)d_in[6];
  const float* Wo = (const float*)d_in[7];
  float* out = (float*)d_out;

  char* ws = (char*)d_ws;
  const size_t MB = 1u << 20;
  unsigned short* qb  = (unsigned short*)(ws + 0 * MB);    // 16 MB each
  unsigned short* kb  = (unsigned short*)(ws + 16 * MB);
  unsigned short* vb  = (unsigned short*)(ws + 32 * MB);
  unsigned short* wqb = (unsigned short*)(ws + 48 * MB);   // 2 MB each
  unsigned short* wkb = (unsigned short*)(ws + 50 * MB);
  unsigned short* wvb = (unsigned short*)(ws + 52 * MB);
  unsigned short* wob = (unsigned short*)(ws + 54 * MB);
  unsigned short* Qp  = (unsigned short*)(ws + 56 * MB);   // 16 MB (pre-scaled)
  unsigned short* Kp  = (unsigned short*)(ws + 72 * MB);   // 16 MB
  unsigned short* VpT = (unsigned short*)(ws + 88 * MB);   // 16 MB, [B*1024, 2048]
  unsigned short* Xp  = (unsigned short*)(ws + 104 * MB);  // 16 MB

  // 3*8192 blocks (q,k,v) + 4*1024 blocks (weights) = 28672
  cast_all<<<dim3(28672), 256, 0, stream>>>(q, k, v, Wq, Wk, Wv, Wo,
                                            qb, kb, vb, wqb, wkb, wvb, wob);

  dim3 gq(64, 8, 3);
  gemm_qkv<<<gq, 256, 0, stream>>>(qb, kb, vb, wqb, wkb, wvb, Qp, Kp, VpT);

  attn<<<dim3(512), 256, 0, stream>>>(Qp, Kp, VpT, Xp);

  dim3 go(64, 8, 1);
  gemm_out<<<go, 256, 0, stream>>>(Xp, wob, out);
}